// Round 7
// baseline (425.379 us; speedup 1.0000x reference)
//
#include <hip/hip_runtime.h>
#include <cfloat>

#define NB 4
#define NN 4096
#define NC 256
#define BR 128                 // rows per band / block

typedef _Float16 f16;
typedef _Float16 f16x8 __attribute__((ext_vector_type(8)));
typedef float f32x16 __attribute__((ext_vector_type(16)));

__device__ __forceinline__ void gl_lds16(const void* g, void* l) {
    __builtin_amdgcn_global_load_lds(
        (const __attribute__((address_space(1))) unsigned int*)g,
        (__attribute__((address_space(3))) unsigned int*)l, 16, 0, 0);
}

// ---- prep: fp32 -> f16 hi/lo, band-transposed + diag ----
// xt[batch][band128][g][r]: g in 0..63 (g = k8*2 + hilo; 16 B = 8 f16), r in 0..127.
// f16 offsets: batch*2097152 + band*65536 + g*1024 + r*8.
// 512 blocks x 32 rows (2 blocks/CU).
__global__ __launch_bounds__(256) void prep_kernel(const float* __restrict__ x,
                                                   f16* __restrict__ xt,
                                                   float* __restrict__ diag) {
    __shared__ f16 LT[64 * 32 * 8];      // [g][r] granules, 32 KB
    const int b = blockIdx.x;            // rows b*32 .. b*32+31
    const int t = threadIdx.x;
    {   // phase 1: r = t>>3, k-octant kq = t&7 (k = kq*32..+31)
        const int r = t >> 3, kq = t & 7;
        const float* src = x + ((size_t)b * 32 + r) * 256 + kq * 32;
        float s = 0.f;
        #pragma unroll
        for (int i = 0; i < 4; ++i) {    // k8-granule = kq*4+i
            const float4 a = *(const float4*)(src + i * 8);
            const float4 c = *(const float4*)(src + i * 8 + 4);
            float vv[8] = {a.x, a.y, a.z, a.w, c.x, c.y, c.z, c.w};
            union { f16 h[8]; f16x8 v; } H, L;
            #pragma unroll
            for (int k = 0; k < 8; ++k) {
                H.h[k] = (f16)vv[k];
                L.h[k] = (f16)(vv[k] - (float)H.h[k]);
                s = fmaf(vv[k], vv[k], s);
            }
            const int g = (kq * 4 + i) * 2;
            *(f16x8*)&LT[((g + 0) * 32 + r) * 8] = H.v;
            *(f16x8*)&LT[((g + 1) * 32 + r) * 8] = L.v;
        }
        s += __shfl_xor(s, 1, 64);
        s += __shfl_xor(s, 2, 64);
        s += __shfl_xor(s, 4, 64);
        if (kq == 0) diag[(size_t)b * 32 + r] = s;
    }
    __syncthreads();
    {   // phase 2: coalesced write-out. r = t&31, granules (t>>5)*8..+7
        const int r = t & 31, g0 = (t >> 5) * 8;
        const int batch = b >> 7;
        const int band  = (b & 127) >> 2;
        const int qtr   = b & 3;         // row offset qtr*32 within band
        f16* dst = xt + (size_t)batch * 2097152 + band * 65536 + qtr * 256;
        #pragma unroll
        for (int gi = 0; gi < 8; ++gi) {
            const int g = g0 + gi;
            *(f16x8*)(dst + g * 1024 + r * 8) = *(const f16x8*)&LT[(g * 32 + r) * 8];
        }
    }
}

// ---------------- main MFMA kernel: barrier-free K-loop ----------------
// Grid 256 = 4 batch x 32 band x 2 j-half; 512 thr (8 waves, 64-col slices).
// Wave tile 128 rows x 64 cols (rt=4, ct=2). A band (128 rows x full K) in LDS;
// B frags global->VGPR, 4-chunk prefetch ring. No K-loop barriers. 1 block/CU.
#define TJ 512
#define JH 2048
#define NQ 64                // 4 j-tiles x 16 K-chunks

struct BFrag { f16x8 h[2]; f16x8 l[2]; };   // 16 VGPRs

__device__ __forceinline__ void load_frag(BFrag& f, const f16* __restrict__ xbt,
                                          int jbase, int qc, int w, int gh, int l31) {
    const int jt = qc >> 4, kc = qc & 15;
    const int g  = kc * 4 + gh * 2;
    #pragma unroll
    for (int ct = 0; ct < 2; ++ct) {
        const int jc = jbase + jt * TJ + w * 64 + ct * 32 + l31;
        const f16* p = xbt + (size_t)(jc >> 7) * 65536 + g * 1024 + (jc & 127) * 8;
        f.h[ct] = *(const f16x8*)p;
        f.l[ct] = *(const f16x8*)(p + 1024);
    }
}

__device__ __forceinline__ void mfma_frag(f32x16 (&acc)[4][2], const f16* AT,
                                          const BFrag& f, int qc, int gh, int l31) {
    const int g = (qc & 15) * 4 + gh * 2;
    #pragma unroll
    for (int rt = 0; rt < 4; ++rt) {
        const f16* pa = AT + g * 1024 + (rt * 32 + l31) * 8;
        const f16x8 ah = *(const f16x8*)pa;
        const f16x8 al = *(const f16x8*)(pa + 1024);
        acc[rt][0] = __builtin_amdgcn_mfma_f32_32x32x16_f16(ah, f.h[0], acc[rt][0], 0, 0, 0);
        acc[rt][1] = __builtin_amdgcn_mfma_f32_32x32x16_f16(ah, f.h[1], acc[rt][1], 0, 0, 0);
        acc[rt][0] = __builtin_amdgcn_mfma_f32_32x32x16_f16(ah, f.l[0], acc[rt][0], 0, 0, 0);
        acc[rt][1] = __builtin_amdgcn_mfma_f32_32x32x16_f16(ah, f.l[1], acc[rt][1], 0, 0, 0);
        acc[rt][0] = __builtin_amdgcn_mfma_f32_32x32x16_f16(al, f.h[0], acc[rt][0], 0, 0, 0);
        acc[rt][1] = __builtin_amdgcn_mfma_f32_32x32x16_f16(al, f.h[1], acc[rt][1], 0, 0, 0);
    }
}

__global__ __launch_bounds__(512, 2) void fcm_mfma(const f16* __restrict__ xt,
                                                   const float* __restrict__ diag,
                                                   float* __restrict__ part) {
    __shared__ f16 AT[65536];            // 128 KB: A band [g][r], r 0..127
    __shared__ float St[BR * 8 * 3];     //  12 KB: per-(row,wave) running top-2

    const int tid   = threadIdx.x;
    const int bx    = blockIdx.x;
    const int batch = (bx & 7) >> 1;     // batch -> XCD pair (L2 locality)
    const int jh    = bx & 1;
    const int band  = bx >> 3;           // 0..31
    const int i0    = band * BR;
    const int jbase = jh * JH;

    const f16* __restrict__ xbt  = xt + (size_t)batch * 2097152;
    const float* __restrict__ db = diag + (size_t)batch * NN;

    const int w    = tid >> 6;           // 0..7: 64-col slice
    const int lane = tid & 63;
    const int gh   = lane >> 5;
    const int l31  = lane & 31;

    BFrag P0, P1, Q0, Q1;
    load_frag(P0, xbt, jbase, 0, w, gh, l31);
    load_frag(P1, xbt, jbase, 1, w, gh, l31);

    // stage A band once: 128 x 1KB contiguous chunks, 16 per wave
    {
        const f16* asrc = xbt + (size_t)band * 65536;
        #pragma unroll
        for (int i = 0; i < 16; ++i) {
            const int m = w * 16 + i;
            gl_lds16(asrc + m * 512 + lane * 8, AT + m * 512 + lane * 8);
        }
    }
    for (int idx = tid; idx < BR * 8 * 3; idx += 512) St[idx] = FLT_MAX;
    __syncthreads();                     // only barrier before the final merge
    load_frag(Q0, xbt, jbase, 2, w, gh, l31);
    load_frag(Q1, xbt, jbase, 3, w, gh, l31);

    f32x16 acc[4][2];
    #pragma unroll
    for (int rt = 0; rt < 4; ++rt)
        #pragma unroll
        for (int ct = 0; ct < 2; ++ct)
            #pragma unroll
            for (int p = 0; p < 16; ++p) acc[rt][ct][p] = 0.f;

    #pragma unroll 1
    for (int q = 0; q < NQ; q += 4) {
        mfma_frag(acc, AT, P0, q, gh, l31);
        mfma_frag(acc, AT, P1, q + 1, gh, l31);
        if (q + 4 < NQ) {
            load_frag(P0, xbt, jbase, q + 4, w, gh, l31);
            load_frag(P1, xbt, jbase, q + 5, w, gh, l31);
        }
        mfma_frag(acc, AT, Q0, q + 2, gh, l31);
        mfma_frag(acc, AT, Q1, q + 3, gh, l31);
        if (q + 6 < NQ) {
            load_frag(Q0, xbt, jbase, q + 6, w, gh, l31);
            load_frag(Q1, xbt, jbase, q + 7, w, gh, l31);
        }

        if ((q & 12) == 12) {            // j-tile complete: fold + reset acc
            const int jt = q >> 4;
            int jcv[2]; float djv[2];
            #pragma unroll
            for (int ct = 0; ct < 2; ++ct) {
                jcv[ct] = jbase + jt * TJ + w * 64 + ct * 32 + l31;
                djv[ct] = db[jcv[ct]];
            }
            float ra1 = FLT_MAX, ra2 = FLT_MAX; int rai = 0x7fffffff;
            float rb1 = FLT_MAX, rb2 = FLT_MAX; int rbi = 0x7fffffff;
            #pragma unroll
            for (int s = 0; s < 64; ++s) {
                const int rt = s >> 4, reg = s & 15;
                const int rg = i0 + rt * 32 + gh * 4 + (reg & 3) + ((reg >> 2) << 3);
                float a1 = FLT_MAX, a2 = FLT_MAX; int ai = 0x7fffffff;
                #pragma unroll
                for (int ct = 0; ct < 2; ++ct) {
                    float v = fmaf(-2.0f, acc[rt][ct][reg], djv[ct]);
                    v = (jcv[ct] == rg) ? FLT_MAX : v;     // mask self
                    const bool lt = v < a1;                // strict: ascending j
                    a2 = fminf(a2, fmaxf(a1, v));
                    a1 = fminf(a1, v);
                    ai = lt ? jcv[ct] : ai;
                }
                #pragma unroll
                for (int msk = 1; msk < 32; msk <<= 1) {   // within gh half
                    const float o1 = __shfl_xor(a1, msk, 64);
                    const float o2 = __shfl_xor(a2, msk, 64);
                    const int   oi = __shfl_xor(ai, msk, 64);
                    const bool take = (o1 < a1) || (o1 == a1 && oi < ai);
                    const float keep = take ? a1 : o1;
                    a2 = fminf(fminf(a2, o2), keep);
                    a1 = take ? o1 : a1;
                    ai = take ? oi : ai;
                }
                const bool sel = (l31 == (s & 31));
                if (s < 32) {
                    ra1 = sel ? a1 : ra1; ra2 = sel ? a2 : ra2; rai = sel ? ai : rai;
                } else {
                    rb1 = sel ? a1 : rb1; rb2 = sel ? a2 : rb2; rbi = sel ? ai : rbi;
                }
            }
            // RMW this wave's St column for the two rows this lane owns
            #pragma unroll
            for (int half = 0; half < 2; ++half) {
                const int s  = half * 32 + l31;
                const int rt = s >> 4, reg = s & 15;
                const int rloc = rt * 32 + gh * 4 + (reg & 3) + ((reg >> 2) << 3);
                const float n1 = half ? rb1 : ra1;
                const float n2 = half ? rb2 : ra2;
                const int   ni = half ? rbi : rai;
                float* p = &St[(rloc * 8 + w) * 3];
                const float o1 = p[0]; const int oi = __float_as_int(p[1]); const float o2 = p[2];
                const bool take = (o1 < n1) || (o1 == n1 && oi < ni);
                const float keep = take ? n1 : o1;
                p[0] = take ? o1 : n1;
                p[1] = __int_as_float(take ? oi : ni);
                p[2] = fminf(fminf(n2, o2), keep);
            }
            #pragma unroll
            for (int rt = 0; rt < 4; ++rt)
                #pragma unroll
                for (int ct = 0; ct < 2; ++ct)
                    #pragma unroll
                    for (int p = 0; p < 16; ++p) acc[rt][ct][p] = 0.f;
        }
    }

    __syncthreads();
    if (tid < BR) {
        float M1 = FLT_MAX, M2 = FLT_MAX; int I1 = 0x7fffffff;
        #pragma unroll
        for (int t = 0; t < 8; ++t) {
            const float* p = &St[(tid * 8 + t) * 3];
            const float o1 = p[0]; const int oi = __float_as_int(p[1]); const float o2 = p[2];
            const bool take = (o1 < M1) || (o1 == M1 && oi < I1);
            const float keep = take ? M1 : o1;
            M2 = fminf(fminf(M2, o2), keep);
            M1 = take ? o1 : M1;
            I1 = take ? oi : I1;
        }
        float* qo = part + (((size_t)batch * NN + i0 + tid) * 2 + jh) * 3;
        qo[0] = M1; qo[1] = __int_as_float(I1); qo[2] = M2;
    }
}

// ---- combine the two j-half partials, compute outputs ----
__global__ __launch_bounds__(256) void combine_kernel(const float* __restrict__ part,
                                                      const float* __restrict__ diag,
                                                      float* __restrict__ out) {
    const int g = blockIdx.x * 256 + threadIdx.x;      // 0..16383
    float M1 = FLT_MAX, M2 = FLT_MAX; int I1 = 0x7fffffff;
    #pragma unroll
    for (int h = 0; h < 2; ++h) {
        const float* p = part + ((size_t)g * 2 + h) * 3;
        const float o1 = p[0]; const int oi = __float_as_int(p[1]); const float o2 = p[2];
        const bool take = (o1 < M1) || (o1 == M1 && oi < I1);
        const float keep = take ? M1 : o1;
        M2 = fminf(fminf(M2, o2), keep);
        M1 = take ? o1 : M1;
        I1 = take ? oi : I1;
    }
    const float di = diag[g];
    const float d1 = sqrtf(fmaxf(di + M1, 0.0f) + 1e-9f);
    const float d2 = sqrtf(fmaxf(di + M2, 0.0f) + 1e-9f);
    const float e  = expf(d1);
    const float pred = (d1 / d2 < 0.6f) ? 2.0f / (1.0f + e)
                                        : 2.0f / (1.0f + 2.0f * e);
    out[g] = pred;
    out[(size_t)NB * NN + g] = (float)I1;
}

// ---------------- fp32 fallback (round-1, known-correct) if ws too small ----------------
__global__ __launch_bounds__(256) void diag_kernel(const float* __restrict__ x,
                                                   float* __restrict__ diag) {
    const int lane = threadIdx.x & 63;
    const int wave = threadIdx.x >> 6;
    const int row  = (blockIdx.x << 2) + wave;
    const float4 v = ((const float4*)(x + (size_t)row * NC))[lane];
    float s = v.x * v.x + v.y * v.y + v.z * v.z + v.w * v.w;
    #pragma unroll
    for (int off = 32; off; off >>= 1) s += __shfl_xor(s, off, 64);
    if (lane == 0) diag[row] = s;
}

#define FTI 64
#define FTJ 256
#define FKC 16

__global__ __launch_bounds__(256) void fcm_fallback(const float* __restrict__ x,
                                                    const float* __restrict__ diag,
                                                    float* __restrict__ out) {
    __shared__ float Asf[FKC * FTI];
    __shared__ float Bsf[FKC * FTJ];
    __shared__ float Dsf[FTJ];
    __shared__ float Scrf[FTI * 32 * 3];

    const int tid = threadIdx.x;
    const int bx  = blockIdx.x;
    const int batch = (bx & 7) >> 1;
    const int tile  = ((bx >> 3) << 1) | (bx & 1);
    const int i0    = tile * FTI;
    const float* __restrict__ xbf = x + (size_t)batch * NN * NC;
    const float* __restrict__ dbf = diag + (size_t)batch * NN;
    const int tx = tid & 31;
    const int ty = tid >> 5;
    const int sr  = tid & 63;
    const int sk0 = (tid >> 6) << 2;

    float m1[8], m2[8]; int i1[8];
    #pragma unroll
    for (int r = 0; r < 8; ++r) { m1[r] = FLT_MAX; m2[r] = FLT_MAX; i1[r] = 0; }

    for (int jt = 0; jt < NN / FTJ; ++jt) {
        const int j0 = jt * FTJ;
        __syncthreads();
        Dsf[tid] = dbf[j0 + tid];
        float acc[8][8];
        #pragma unroll
        for (int r = 0; r < 8; ++r)
            #pragma unroll
            for (int c = 0; c < 8; ++c) acc[r][c] = 0.0f;
        float4 pa  = *(const float4*)(xbf + (size_t)(i0 + sr) * NC + sk0);
        const float* bsrc = xbf + (size_t)(j0 + tid) * NC;
        float4 pb0 = *(const float4*)(bsrc + 0);
        float4 pb1 = *(const float4*)(bsrc + 4);
        float4 pb2 = *(const float4*)(bsrc + 8);
        float4 pb3 = *(const float4*)(bsrc + 12);
        for (int kc = 0; kc < NC / FKC; ++kc) {
            __syncthreads();
            Asf[(sk0 + 0) * FTI + sr] = pa.x;
            Asf[(sk0 + 1) * FTI + sr] = pa.y;
            Asf[(sk0 + 2) * FTI + sr] = pa.z;
            Asf[(sk0 + 3) * FTI + sr] = pa.w;
            Bsf[ 0 * FTJ + tid] = pb0.x; Bsf[ 1 * FTJ + tid] = pb0.y;
            Bsf[ 2 * FTJ + tid] = pb0.z; Bsf[ 3 * FTJ + tid] = pb0.w;
            Bsf[ 4 * FTJ + tid] = pb1.x; Bsf[ 5 * FTJ + tid] = pb1.y;
            Bsf[ 6 * FTJ + tid] = pb1.z; Bsf[ 7 * FTJ + tid] = pb1.w;
            Bsf[ 8 * FTJ + tid] = pb2.x; Bsf[ 9 * FTJ + tid] = pb2.y;
            Bsf[10 * FTJ + tid] = pb2.z; Bsf[11 * FTJ + tid] = pb2.w;
            Bsf[12 * FTJ + tid] = pb3.x; Bsf[13 * FTJ + tid] = pb3.y;
            Bsf[14 * FTJ + tid] = pb3.z; Bsf[15 * FTJ + tid] = pb3.w;
            if (kc + 1 < NC / FKC) {
                const int kb = (kc + 1) * FKC;
                pa  = *(const float4*)(xbf + (size_t)(i0 + sr) * NC + kb + sk0);
                pb0 = *(const float4*)(bsrc + kb + 0);
                pb1 = *(const float4*)(bsrc + kb + 4);
                pb2 = *(const float4*)(bsrc + kb + 8);
                pb3 = *(const float4*)(bsrc + kb + 12);
            }
            __syncthreads();
            #pragma unroll
            for (int k = 0; k < FKC; ++k) {
                float av[8], bv[8];
                *(float4*)&av[0] = *(const float4*)&Asf[k * FTI + ty * 8];
                *(float4*)&av[4] = *(const float4*)&Asf[k * FTI + ty * 8 + 4];
                *(float4*)&bv[0] = *(const float4*)&Bsf[k * FTJ + tx * 8];
                *(float4*)&bv[4] = *(const float4*)&Bsf[k * FTJ + tx * 8 + 4];
                #pragma unroll
                for (int r = 0; r < 8; ++r)
                    #pragma unroll
                    for (int c = 0; c < 8; ++c)
                        acc[r][c] = fmaf(av[r], bv[c], acc[r][c]);
            }
        }
        #pragma unroll
        for (int c = 0; c < 8; ++c) {
            const int j = j0 + tx * 8 + c;
            const float dj = Dsf[tx * 8 + c];
            #pragma unroll
            for (int r = 0; r < 8; ++r) {
                const int ig = i0 + ty * 8 + r;
                float v = fmaf(-2.0f, acc[r][c], dj);
                v = (j == ig) ? FLT_MAX : v;
                const bool lt = v < m1[r];
                m2[r] = fminf(m2[r], fmaxf(m1[r], v));
                m1[r] = fminf(m1[r], v);
                i1[r] = lt ? j : i1[r];
            }
        }
    }
    __syncthreads();
    #pragma unroll
    for (int r = 0; r < 8; ++r) {
        float* s = &Scrf[((ty * 8 + r) * 32 + tx) * 3];
        s[0] = m1[r]; s[1] = __int_as_float(i1[r]); s[2] = m2[r];
    }
    __syncthreads();
    if (tid < FTI) {
        float M1 = FLT_MAX, M2 = FLT_MAX; int I1 = 0;
        for (int t = 0; t < 32; ++t) {
            const float* s = &Scrf[(tid * 32 + t) * 3];
            const float v1 = s[0]; const int ii = __float_as_int(s[1]);
            const float v2 = s[2];
            if (v1 < M1 || (v1 == M1 && ii < I1)) {
                M2 = fminf(M2, M1); M1 = v1; I1 = ii;
            } else {
                M2 = fminf(M2, v1);
            }
            M2 = fminf(M2, v2);
        }
        const int   gi = i0 + tid;
        const float di = dbf[gi];
        const float d1 = sqrtf(fmaxf(di + M1, 0.0f) + 1e-9f);
        const float d2 = sqrtf(fmaxf(di + M2, 0.0f) + 1e-9f);
        const float e  = expf(d1);
        const float pred = (d1 / d2 < 0.6f) ? 2.0f / (1.0f + e)
                                            : 2.0f / (1.0f + 2.0f * e);
        out[(size_t)batch * NN + gi] = pred;
        out[(size_t)NB * NN + (size_t)batch * NN + gi] = (float)I1;
    }
}

extern "C" void kernel_launch(void* const* d_in, const int* in_sizes, int n_in,
                              void* d_out, int out_size, void* d_ws, size_t ws_size,
                              hipStream_t stream) {
    const float* x = (const float*)d_in[0];
    float* out     = (float*)d_out;
    const size_t n_elem = (size_t)NB * NN * NC;
    const size_t need = n_elem * 4                       // band-transposed hi/lo f16
                      + (size_t)NB * NN * 4              // diag
                      + (size_t)NB * NN * 2 * 3 * 4;     // per-half partials
    if (ws_size >= need) {
        f16*   xt   = (f16*)d_ws;
        float* diag = (float*)(xt + (size_t)NB * NN * 512);
        float* part = diag + (size_t)NB * NN;
        prep_kernel<<<dim3(NB * NN / 32), dim3(256), 0, stream>>>(x, xt, diag);
        fcm_mfma<<<dim3(256), dim3(512), 0, stream>>>(xt, diag, part);
        combine_kernel<<<dim3(NB * NN / 256), dim3(256), 0, stream>>>(part, diag, out);
    } else {
        float* diag = (float*)d_ws;
        diag_kernel<<<dim3(NB * NN / 4), dim3(256), 0, stream>>>(x, diag);
        fcm_fallback<<<dim3(256), dim3(256), 0, stream>>>(x, diag, out);
    }
}